// Round 9
// baseline (192.986 us; speedup 1.0000x reference)
//
#include <hip/hip_runtime.h>
#include <hip/hip_bf16.h>

// Problem constants
#define BATCH 256
#define CDIM  512
#define NPOS  49        // 7*7 attention positions
#define ASTRIDE 520     // fallback-kernel LDS stride

typedef __attribute__((ext_vector_type(8))) short bf16x8_t;  // MFMA A/B frag (4 VGPRs)
typedef __attribute__((ext_vector_type(4))) float f32x4_t;   // MFMA C/D frag

// ---------------------------------------------------------------------------
// ws layout (fast path).  pooled & Wab are stored in MFMA FRAGMENT layout:
//   chunk(tile, kb, lane) holds M[tile*16 + (lane&15)][kb*32 + (lane>>4)*8 .. +7]
//   Wab_f    bf16 [32 cg2][16 kb][64 lane][8]  @ 0         (524288)
//   pooled_f bf16 [256 b][16 kb][4 rg][64][8]  @ 524288    (16777216)
//   ahb      f32  [256][512]                   @ 17301504  (524288)
//   scores   f32  [256][64]                    @ 17825792  (65536)
//   counters int  [256]                        @ 17891328  (1024)
// total 17892352 B
// ---------------------------------------------------------------------------
#define WS_NEED 17892352u

__device__ __forceinline__ void load_lds16(const void* g, void* l) {
    __builtin_amdgcn_global_load_lds(
        (const __attribute__((address_space(1))) void*)g,
        (__attribute__((address_space(3))) void*)l, 16, 0, 0);
}

// ===========================================================================
// K1 mega-kernel (grid 4177): independent block roles, small roles first.
//   bid 0..15  : zero scores (4096 float4)
//   bid 16     : zero counters
//   bid 17..48 : Wa fp32 -> bf16 fragment-layout Wab_f (one 16-row cg2 each)
//   bid 49..80 : MFMA tile GEMM  ahb = h @ Wh^T + ba + bh (64x64 tile)
//   bid >= 81  : 2x2 avg-pool att_v -> pooled_f (fragment layout via LDS
//                transpose; pad rows 49..63 left as junk — rows are
//                independent in MFMA and never read downstream)
// ===========================================================================
__global__ __launch_bounds__(256, 6) void k1_pool_prep_ah(
    const float* __restrict__ att_v,   // [256,512,14,14]
    const float* __restrict__ h,       // [256,512]
    const float* __restrict__ Wa,      // [512,512]
    const float* __restrict__ Wh,      // [512,512]
    const float* __restrict__ ba, const float* __restrict__ bh,
    __hip_bfloat16* __restrict__ pooled,   // fragment layout
    __hip_bfloat16* __restrict__ Wab,      // fragment layout
    float* __restrict__ ahb,
    float* __restrict__ scores,
    int* __restrict__ counters) {
    __shared__ char smem[25088];
    const int bid = blockIdx.x;
    const int t   = threadIdx.x;

    if (bid < 16) {
        ((float4*)scores)[bid * 256 + t] = (float4){0.f, 0.f, 0.f, 0.f};
    } else if (bid == 16) {
        if (t < 64) ((float4*)counters)[t] = (float4){0.f, 0.f, 0.f, 0.f};
    } else if (bid < 49) {
        // ---------------- Wa -> bf16 fragment layout ----------------
        const int cg2 = bid - 17;                    // 16-row group of Wa
        __hip_bfloat16* wl = (__hip_bfloat16*)smem;  // [16][520] bf16 (16640 B)
        const float4* wsrc = (const float4*)(Wa + (size_t)cg2 * 16 * CDIM);
        #pragma unroll
        for (int k = 0; k < 8; ++k) {
            const int idx = t + k * 256;             // 0..2047 float4
            float4 v = wsrc[idx];
            const int d = idx >> 7, cf = (idx & 127) * 4;
            __hip_bfloat16* w = &wl[d * 520 + cf];
            w[0] = __float2bfloat16(v.x); w[1] = __float2bfloat16(v.y);
            w[2] = __float2bfloat16(v.z); w[3] = __float2bfloat16(v.w);
        }
        __syncthreads();
        #pragma unroll
        for (int e = 0; e < 4; ++e) {
            const int chunk = t + e * 256;           // 0..1023 = kb*64 + lane
            const int kb = chunk >> 6, lane = chunk & 63;
            bf16x8_t v = *(const bf16x8_t*)
                &wl[(lane & 15) * 520 + kb * 32 + (lane >> 4) * 8];
            *(bf16x8_t*)&Wab[(size_t)cg2 * 8192 + chunk * 8] = v;
        }
    } else if (bid < 81) {
        // ---------------- ah MFMA tile (fp32 inputs, inline convert) --------
        const int rel = bid - 49;                    // 0..31
        const int mt = rel & 3;                      // 4 x 64 over 256 b-rows
        const int nt = rel >> 2;                     // 8 x 64 over 512 d-cols
        const int m0 = mt * 64, n0 = nt * 64;
        __hip_bfloat16* aT = (__hip_bfloat16*)smem;          // 64 x 32 (4 KB)
        __hip_bfloat16* bT = (__hip_bfloat16*)smem + 2048;   // 64 x 32 (4 KB)
        const int wave = t >> 6, lane = t & 63;
        const int wm = wave & 1, wn = wave >> 1;
        const int q = lane >> 4, r = lane & 15;
        const int row = t >> 2, cseg = (t & 3) * 8;
        const float* hg = h  + (size_t)(m0 + row) * CDIM + cseg;
        const float* wg = Wh + (size_t)(n0 + row) * CDIM + cseg;

        f32x4_t acc[2][2];
        #pragma unroll
        for (int rt = 0; rt < 2; ++rt)
            #pragma unroll
            for (int ct = 0; ct < 2; ++ct) acc[rt][ct] = (f32x4_t){0.f, 0.f, 0.f, 0.f};

        for (int ks = 0; ks < 16; ++ks) {
            float4 a0 = *(const float4*)(hg + ks * 32);
            float4 a1 = *(const float4*)(hg + ks * 32 + 4);
            float4 b0 = *(const float4*)(wg + ks * 32);
            float4 b1 = *(const float4*)(wg + ks * 32 + 4);
            union { bf16x8_t v; __hip_bfloat16 e[8]; } ua, ub;
            ua.e[0] = __float2bfloat16(a0.x); ua.e[1] = __float2bfloat16(a0.y);
            ua.e[2] = __float2bfloat16(a0.z); ua.e[3] = __float2bfloat16(a0.w);
            ua.e[4] = __float2bfloat16(a1.x); ua.e[5] = __float2bfloat16(a1.y);
            ua.e[6] = __float2bfloat16(a1.z); ua.e[7] = __float2bfloat16(a1.w);
            ub.e[0] = __float2bfloat16(b0.x); ub.e[1] = __float2bfloat16(b0.y);
            ub.e[2] = __float2bfloat16(b0.z); ub.e[3] = __float2bfloat16(b0.w);
            ub.e[4] = __float2bfloat16(b1.x); ub.e[5] = __float2bfloat16(b1.y);
            ub.e[6] = __float2bfloat16(b1.z); ub.e[7] = __float2bfloat16(b1.w);
            __syncthreads();
            *(bf16x8_t*)&aT[row * 32 + cseg] = ua.v;
            *(bf16x8_t*)&bT[row * 32 + cseg] = ub.v;
            __syncthreads();
            bf16x8_t af[2], bf[2];
            #pragma unroll
            for (int rt = 0; rt < 2; ++rt)
                af[rt] = *(const bf16x8_t*)&aT[(wm * 32 + rt * 16 + r) * 32 + q * 8];
            #pragma unroll
            for (int ct = 0; ct < 2; ++ct)
                bf[ct] = *(const bf16x8_t*)&bT[(wn * 32 + ct * 16 + r) * 32 + q * 8];
            #pragma unroll
            for (int rt = 0; rt < 2; ++rt)
                #pragma unroll
                for (int ct = 0; ct < 2; ++ct)
                    acc[rt][ct] = __builtin_amdgcn_mfma_f32_16x16x32_bf16(
                        af[rt], bf[ct], acc[rt][ct], 0, 0, 0);
        }
        #pragma unroll
        for (int ct = 0; ct < 2; ++ct) {
            const int col = n0 + wn * 32 + ct * 16 + r;
            const float bias = ba[col] + bh[col];
            #pragma unroll
            for (int rt = 0; rt < 2; ++rt)
                #pragma unroll
                for (int rg = 0; rg < 4; ++rg) {
                    const int orow = m0 + wm * 32 + rt * 16 + q * 4 + rg;
                    ahb[(size_t)orow * CDIM + col] = acc[rt][ct][rg] + bias;
                }
        }
    } else {
        // ---------------- pool -> fragment layout ----------------
        const int rel = bid - 81;
        const int b  = rel >> 4;
        const int cg = rel & 15;                     // channel group == kb
        const float4* src = (const float4*)(att_v + ((size_t)b * CDIM + cg * 32) * 196);
        #pragma unroll
        for (int k = 0; k < 7; ++k) {
            const int idx = t + k * 256;
            if (idx < 1568) load_lds16(src + idx, smem + idx * 16);
        }
        __syncthreads();
        const int i = t >> 5;                        // pooled row block (7 active)
        const int c = t & 31;                        // local channel
        float p[7];
        if (i < 7) {
            const float4* fp = (const float4*)smem + (c * 49 + 7 * i);
            float4 f0 = fp[0], f1 = fp[1], f2 = fp[2], f3 = fp[3];
            float4 f4 = fp[4], f5 = fp[5], f6 = fp[6];
            p[0] = f0.x + f0.y + f3.z + f3.w;
            p[1] = f0.z + f0.w + f4.x + f4.y;
            p[2] = f1.x + f1.y + f4.z + f4.w;
            p[3] = f1.z + f1.w + f5.x + f5.y;
            p[4] = f2.x + f2.y + f5.z + f5.w;
            p[5] = f2.z + f2.w + f6.x + f6.y;
            p[6] = f3.x + f3.y + f6.z + f6.w;
        }
        __syncthreads();                             // all float4 reads done
        __hip_bfloat16* pl = (__hip_bfloat16*)smem;  // p_lds[c*65 + n], 4160 B
        if (i < 7) {
            #pragma unroll
            for (int j = 0; j < 7; ++j)
                pl[c * 65 + i * 7 + j] = __float2bfloat16(p[j] * 0.25f);
        }
        __syncthreads();
        // fragment-chunk write: thread t = rg*64 + lane; rows >=49 are junk.
        {
            const int rg = t >> 6, lane = t & 63;
            const int m = lane & 15, qd = lane >> 4;
            union { bf16x8_t v; __hip_bfloat16 e[8]; } u;
            #pragma unroll
            for (int e = 0; e < 8; ++e)
                u.e[e] = pl[(qd * 8 + e) * 65 + rg * 16 + m];
            __hip_bfloat16* outp =
                pooled + ((((size_t)b * 16 + cg) * 4 + rg) << 9) + lane * 8;
            *(bf16x8_t*)outp = u.v;
        }
    }
}

// ===========================================================================
// K2 gemm_score_direct: one block = (batch b, 128-col tile nt).  grid 1024.
// NO LDS, NO barriers in the K-loop: both operands read as coalesced
// global_load_dwordx4 fragment chunks (A from pooled_f via L3, B from Wab_f
// via L2) — compiler free to software-pipeline.  Epilogue + per-batch atomic
// completion protocol identical to round 8 (proven).
// ===========================================================================
__global__ __launch_bounds__(256, 4) void gemm_score_direct(
    const __hip_bfloat16* __restrict__ A,   // pooled_f
    const __hip_bfloat16* __restrict__ Bw,  // Wab_f
    const float* __restrict__ ahb,          // [256][512]
    const float* __restrict__ Wd,           // [512]
    float* __restrict__ scores,             // [256][64]
    int* __restrict__ counters,             // [256]
    float* __restrict__ out) {              // [256][512]
    __shared__ float s_raw[NPOS];
    __shared__ float w_w[NPOS];
    __shared__ int   last_flag;
    const int b  = blockIdx.x >> 2;
    const int nt = blockIdx.x & 3;
    const int t = threadIdx.x;
    const int wave = t >> 6, lane = t & 63;
    const int wm = wave & 1, wn = wave >> 1;
    const int q = lane >> 4, r = lane & 15;
    const int n0 = nt * 128;

    const __hip_bfloat16* Ab = A + ((size_t)b << 15);          // b*16*4*512
    const __hip_bfloat16* Bb = Bw + ((size_t)(nt * 8 + wn * 4) << 13);  // cg2*16*512

    f32x4_t acc[2][4];
    #pragma unroll
    for (int rt = 0; rt < 2; ++rt)
        #pragma unroll
        for (int ct = 0; ct < 4; ++ct) acc[rt][ct] = (f32x4_t){0.f, 0.f, 0.f, 0.f};

    #pragma unroll 4
    for (int kb = 0; kb < 16; ++kb) {
        bf16x8_t af[2], bf[4];
        #pragma unroll
        for (int rt = 0; rt < 2; ++rt)
            af[rt] = *(const bf16x8_t*)&Ab[((kb * 4 + wm * 2 + rt) << 9) + lane * 8];
        #pragma unroll
        for (int ct = 0; ct < 4; ++ct)
            bf[ct] = *(const bf16x8_t*)&Bb[(((ct << 4) + kb) << 9) + lane * 8];
        #pragma unroll
        for (int rt = 0; rt < 2; ++rt)
            #pragma unroll
            for (int ct = 0; ct < 4; ++ct)
                acc[rt][ct] = __builtin_amdgcn_mfma_f32_16x16x32_bf16(
                    af[rt], bf[ct], acc[rt][ct], 0, 0, 0);
    }

    // --- tanh*Wd column reduction.  Rows: wm*32+rt*16+q*4+rg; cols: n0+wn*64+ct*16+r.
    float rsum[2][4];
    #pragma unroll
    for (int rt = 0; rt < 2; ++rt)
        #pragma unroll
        for (int rg = 0; rg < 4; ++rg) rsum[rt][rg] = 0.f;

    const float* ahp = ahb + (size_t)b * CDIM;
    #pragma unroll
    for (int ct = 0; ct < 4; ++ct) {
        const int col = n0 + wn * 64 + ct * 16 + r;
        const float ah = ahp[col];
        const float wd = Wd[col];
        #pragma unroll
        for (int rt = 0; rt < 2; ++rt)
            #pragma unroll
            for (int rg = 0; rg < 4; ++rg) {
                float x = acc[rt][ct][rg] + ah;
                float e = __expf(2.f * x);               // tanh = 1 - 2/(e^{2x}+1)
                rsum[rt][rg] += (1.f - 2.f / (e + 1.f)) * wd;
            }
    }
    #pragma unroll
    for (int m = 1; m < 16; m <<= 1)
        #pragma unroll
        for (int rt = 0; rt < 2; ++rt)
            #pragma unroll
            for (int rg = 0; rg < 4; ++rg)
                rsum[rt][rg] += __shfl_xor(rsum[rt][rg], m, 64);
    if (r == 0) {
        float* sb = scores + b * 64;
        #pragma unroll
        for (int rt = 0; rt < 2; ++rt)
            #pragma unroll
            for (int rg = 0; rg < 4; ++rg) {
                const int row = wm * 32 + rt * 16 + q * 4 + rg;
                if (row < NPOS) atomicAdd(&sb[row], rsum[rt][rg]);
            }
    }

    // --- per-batch completion via atomics only (no __threadfence — its L2
    // writeback/invalidate serialized catastrophically in round 7).
    asm volatile("s_waitcnt vmcnt(0)" ::: "memory");
    __syncthreads();
    if (t == 0) last_flag = (atomicAdd(&counters[b], 1) == 3);
    __syncthreads();
    if (!last_flag) return;

    if (t < NPOS) s_raw[t] = atomicAdd(&scores[b * 64 + t], 0.0f);
    __syncthreads();
    if (t < NPOS) {
        float vmax = -3.0e38f;
        #pragma unroll
        for (int n = 0; n < NPOS; ++n) vmax = fmaxf(vmax, s_raw[n]);
        float S = 0.f;
        #pragma unroll
        for (int n = 0; n < NPOS; ++n) S += __expf(s_raw[n] - vmax);
        w_w[t] = __expf(s_raw[t] - vmax) / S;
    }
    __syncthreads();

    // Weighted channel sum from fragment layout (L2/L3-hot):
    // val(n,c) = Ab[((c>>5)*4 + (n>>4))*512 + ((n&15) + ((c>>3)&3)*16)*8 + (c&7)]
    {
        const int c0 = t, c1 = t + 256;
        const int k0 = ((c0 >> 5) << 11) + (((c0 >> 3) & 3) << 7) + (c0 & 7);
        const int k1 = ((c1 >> 5) << 11) + (((c1 >> 3) & 3) << 7) + (c1 & 7);
        float a0 = 0.f, a1 = 0.f;
        #pragma unroll
        for (int n = 0; n < NPOS; ++n) {
            const float w = w_w[n];
            const int ro = ((n >> 4) << 9) + ((n & 15) << 3);
            a0 += w * __bfloat162float(Ab[k0 + ro]);
            a1 += w * __bfloat162float(Ab[k1 + ro]);
        }
        out[b * CDIM + c0] = a0;
        out[b * CDIM + c1] = a1;
    }
}

// ===========================================================================
// Fallback path (round-1, 1 MB ws) — used only if ws too small.
// ===========================================================================
__global__ void prep_convert(const float* __restrict__ Wa,
                             const float* __restrict__ Wh,
                             __hip_bfloat16* __restrict__ Wab,
                             __hip_bfloat16* __restrict__ Whb) {
    int gid = blockIdx.x * blockDim.x + threadIdx.x;
    const int quarter = (CDIM * CDIM) / 4;
    const float4* src; __hip_bfloat16* dst; int idx;
    if (gid < quarter) { src = (const float4*)Wa; dst = Wab; idx = gid; }
    else               { src = (const float4*)Wh; dst = Whb; idx = gid - quarter; }
    float4 v = src[idx];
    dst[idx * 4 + 0] = __float2bfloat16(v.x);
    dst[idx * 4 + 1] = __float2bfloat16(v.y);
    dst[idx * 4 + 2] = __float2bfloat16(v.z);
    dst[idx * 4 + 3] = __float2bfloat16(v.w);
}

__global__ __launch_bounds__(512, 2) void att_spp_main(
    const float* __restrict__ att_v, const float* __restrict__ h,
    const float* __restrict__ ba, const float* __restrict__ bh,
    const float* __restrict__ Wd,
    const __hip_bfloat16* __restrict__ Wab, const __hip_bfloat16* __restrict__ Whb,
    float* __restrict__ out) {
    __shared__ __hip_bfloat16 a_lds[64 * ASTRIDE];
    __shared__ __hip_bfloat16 h_lds[CDIM];
    __shared__ float babh_lds[CDIM];
    __shared__ float wd_lds[CDIM];
    __shared__ float scores_lds[64];
    __shared__ float weights_lds[NPOS];
    const int b = blockIdx.x, t = threadIdx.x;
    h_lds[t]    = __float2bfloat16(h[b * CDIM + t]);
    babh_lds[t] = ba[t] + bh[t];
    wd_lds[t]   = Wd[t];
    if (t < 64) scores_lds[t] = 0.f;
    for (int idx = t; idx < (64 - NPOS) * ASTRIDE; idx += 512)
        a_lds[NPOS * ASTRIDE + idx] = __float2bfloat16(0.f);
    {
        const int jj = t & 7, g = t >> 3;
        const float2* att2 = (const float2*)(att_v + (size_t)b * CDIM * 196);
        if (jj < 7) {
            for (int ci = 0; ci < 8; ++ci) {
                const int c = g + (ci << 6), cbase = c * 98;
                #pragma unroll
                for (int i = 0; i < 7; ++i) {
                    float2 v0 = att2[cbase + i * 14 + jj];
                    float2 v1 = att2[cbase + i * 14 + 7 + jj];
                    a_lds[(i * 7 + jj) * ASTRIDE + c] =
                        __float2bfloat16((v0.x + v0.y + v1.x + v1.y) * 0.25f);
                }
            }
        }
    }
    __syncthreads();
    const int wave = t >> 6, lane = t & 63, q = lane >> 4, r = lane & 15;
    f32x4_t acc[4][4];
    #pragma unroll
    for (int rt = 0; rt < 4; ++rt)
        #pragma unroll
        for (int ct = 0; ct < 4; ++ct) acc[rt][ct] = (f32x4_t){0.f,0.f,0.f,0.f};
    const int dBase = wave * 64 + r;
    for (int ks = 0; ks < 16; ++ks) {
        const int k0 = ks * 32 + q * 8;
        bf16x8_t af[4], bf[4];
        #pragma unroll
        for (int rt = 0; rt < 4; ++rt)
            af[rt] = *(const bf16x8_t*)&a_lds[(rt * 16 + r) * ASTRIDE + k0];
        #pragma unroll
        for (int ct = 0; ct < 4; ++ct)
            bf[ct] = *(const bf16x8_t*)&Wab[(size_t)(dBase + ct * 16) * CDIM + k0];
        #pragma unroll
        for (int rt = 0; rt < 4; ++rt)
            #pragma unroll
            for (int ct = 0; ct < 4; ++ct)
                acc[rt][ct] = __builtin_amdgcn_mfma_f32_16x16x32_bf16(
                    af[rt], bf[ct], acc[rt][ct], 0, 0, 0);
    }
    for (int ks = 0; ks < 16; ++ks) {
        const int k0 = ks * 32 + q * 8;
        bf16x8_t af = *(const bf16x8_t*)&h_lds[k0];
        bf16x8_t bf[4];
        #pragma unroll
        for (int ct = 0; ct < 4; ++ct)
            bf[ct] = *(const bf16x8_t*)&Whb[(size_t)(dBase + ct * 16) * CDIM + k0];
        #pragma unroll
        for (int rt = 0; rt < 4; ++rt)
            #pragma unroll
            for (int ct = 0; ct < 4; ++ct)
                acc[rt][ct] = __builtin_amdgcn_mfma_f32_16x16x32_bf16(
                    af, bf[ct], acc[rt][ct], 0, 0, 0);
    }
    float part[4][4];
    #pragma unroll
    for (int rt = 0; rt < 4; ++rt)
        #pragma unroll
        for (int rg = 0; rg < 4; ++rg) part[rt][rg] = 0.f;
    #pragma unroll
    for (int ct = 0; ct < 4; ++ct) {
        const int d = dBase + ct * 16;
        const float bias = babh_lds[d], wd = wd_lds[d];
        #pragma unroll
        for (int rt = 0; rt < 4; ++rt)
            #pragma unroll
            for (int rg = 0; rg < 4; ++rg) {
                float x = acc[rt][ct][rg] + bias;
                float e = __expf(2.f * x);
                part[rt][rg] += (1.f - 2.f / (e + 1.f)) * wd;
            }
    }
    #pragma unroll
    for (int m = 1; m < 16; m <<= 1)
        #pragma unroll
        for (int rt = 0; rt < 4; ++rt)
            #pragma unroll
            for (int rg = 0; rg < 4; ++rg)
                part[rt][rg] += __shfl_xor(part[rt][rg], m, 64);
    if (r == 0) {
        #pragma unroll
        for (int rt = 0; rt < 4; ++rt)
            #pragma unroll
            for (int rg = 0; rg < 4; ++rg)
                atomicAdd(&scores_lds[rt * 16 + q * 4 + rg], part[rt][rg]);
    }
    __syncthreads();
    if (wave == 0) {
        float v = (lane < NPOS) ? scores_lds[lane] : -3.0e38f;
        float vmax = v;
        #pragma unroll
        for (int m = 1; m < 64; m <<= 1) vmax = fmaxf(vmax, __shfl_xor(vmax, m, 64));
        float e = (lane < NPOS) ? __expf(v - vmax) : 0.f;
        float s = e;
        #pragma unroll
        for (int m = 1; m < 64; m <<= 1) s += __shfl_xor(s, m, 64);
        if (lane < NPOS) weights_lds[lane] = e / s;
    }
    __syncthreads();
    float sum = 0.f;
    #pragma unroll
    for (int n = 0; n < NPOS; ++n)
        sum += __bfloat162float(a_lds[n * ASTRIDE + t]) * weights_lds[n];
    out[b * CDIM + t] = sum;
}

// ===========================================================================
extern "C" void kernel_launch(void* const* d_in, const int* in_sizes, int n_in,
                              void* d_out, int out_size, void* d_ws, size_t ws_size,
                              hipStream_t stream) {
    const float* att_v = (const float*)d_in[0];
    const float* h     = (const float*)d_in[1];
    const float* Wa    = (const float*)d_in[2];
    const float* ba    = (const float*)d_in[3];
    const float* Wh    = (const float*)d_in[4];
    const float* bh    = (const float*)d_in[5];
    const float* Wd    = (const float*)d_in[6];
    // d_in[7] = bd: dropped (softmax shift-invariant)

    if (ws_size >= WS_NEED) {
        char* ws = (char*)d_ws;
        __hip_bfloat16* Wab     = (__hip_bfloat16*)(ws);
        __hip_bfloat16* pooled  = (__hip_bfloat16*)(ws + 524288);
        float*          ahb     = (float*)(ws + 17301504);
        float*          scores  = (float*)(ws + 17825792);
        int*            counters= (int*)(ws + 17891328);

        k1_pool_prep_ah<<<4177, 256, 0, stream>>>(att_v, h, Wa, Wh, ba, bh,
                                                  pooled, Wab, ahb,
                                                  scores, counters);
        gemm_score_direct<<<1024, 256, 0, stream>>>(pooled, Wab, ahb, Wd,
                                                    scores, counters,
                                                    (float*)d_out);
    } else {
        __hip_bfloat16* Wab = (__hip_bfloat16*)d_ws;
        __hip_bfloat16* Whb = Wab + (size_t)CDIM * CDIM;
        prep_convert<<<512, 256, 0, stream>>>(Wa, Wh, Wab, Whb);
        att_spp_main<<<BATCH, 512, 0, stream>>>(att_v, h, ba, bh, Wd, Wab, Whb,
                                                (float*)d_out);
    }
}